// Round 1
// baseline (739.490 us; speedup 1.0000x reference)
//
#include <hip/hip_runtime.h>
#include <math.h>

#define Bn 4
#define Dn 512
#define Sn 2048
#define Ln 8921
#define Lpad 8960   // Ln rounded up to 128

typedef short bf16x8 __attribute__((ext_vector_type(8)));
typedef float f32x4 __attribute__((ext_vector_type(4)));

__device__ __forceinline__ float elu1(float x) {
    return x > 0.f ? x : expm1f(x);
}

// f32 -> bf16 round-to-nearest-even, result in low 16 bits
__device__ __forceinline__ unsigned f2bf(float f) {
    unsigned u = __float_as_uint(f);
    u += 0x7FFFu + ((u >> 16) & 1u);
    return u >> 16;
}
__device__ __forceinline__ unsigned pack2(float a, float b) {
    return f2bf(a) | (f2bf(b) << 16);
}
// truncating pack (fallback path only, R2-proven)
__device__ __forceinline__ unsigned pack_bf_trunc(float lo, float hi) {
    return __builtin_amdgcn_perm(__float_as_uint(hi), __float_as_uint(lo), 0x07060302u);
}
__device__ __forceinline__ void gld_lds16(const void* g, void* l) {
    __builtin_amdgcn_global_load_lds((const __attribute__((address_space(1))) int*)g,
                                     (__attribute__((address_space(3))) int*)l, 16, 0, 0);
}

// ---------------------------------------------------------------------------
// H [B][D][S] f32 -> Ht [B][S][D] bf16 (LDS 64x64 tile transpose)
// ---------------------------------------------------------------------------
__global__ __launch_bounds__(256) void h_transpose(const float* __restrict__ H,
                                                   short* __restrict__ Ht) {
    int b = blockIdx.z;
    int s0 = blockIdx.x * 64, d0 = blockIdx.y * 64;
    __shared__ float tile[64][65];
    int t = threadIdx.x;
    int r = t >> 4, c4 = (t & 15) * 4;
    const float* Hb = H + (size_t)b * Dn * Sn;
#pragma unroll
    for (int i = 0; i < 4; ++i) {
        float4 v = *(const float4*)(Hb + (size_t)(d0 + i * 16 + r) * Sn + s0 + c4);
        *(float4*)&tile[i * 16 + r][c4] = v;  // tile[d][s]
    }
    __syncthreads();
#pragma unroll
    for (int i = 0; i < 4; ++i) {
        int srow = i * 16 + r;
        float v0 = tile[c4 + 0][srow], v1 = tile[c4 + 1][srow];
        float v2 = tile[c4 + 2][srow], v3 = tile[c4 + 3][srow];
        uint2 o = make_uint2(pack2(v0, v1), pack2(v2, v3));
        *(uint2*)(Ht + ((size_t)b * Sn + s0 + srow) * Dn + d0 + c4) = o;
    }
}

// ---------------------------------------------------------------------------
// plain f32 -> bf16 cvt (n8 = elems/8, exact multiple)
// ---------------------------------------------------------------------------
__global__ __launch_bounds__(256) void f32_to_bf16(const float* __restrict__ src,
                                                   short* __restrict__ dst, int n8) {
    int id = blockIdx.x * 256 + threadIdx.x;
    if (id >= n8) return;
    const float* s = src + (size_t)id * 8;
    float4 a = *(const float4*)s;
    float4 b = *(const float4*)(s + 4);
    uint4 o = {pack2(a.x, a.y), pack2(a.z, a.w), pack2(b.x, b.y), pack2(b.z, b.w)};
    *(uint4*)(dst + (size_t)id * 8) = o;
}

// Q f32 [Ln][Dn] -> bf16 [Lpad][Dn], pad rows zeroed
__global__ __launch_bounds__(256) void q_to_bf16(const float* __restrict__ Q,
                                                 short* __restrict__ Qb) {
    int id = blockIdx.x * 256 + threadIdx.x;  // Lpad*64 ids, 8 elems each
    int row = id >> 6, c = (id & 63) * 8;
    uint4 o = {0, 0, 0, 0};
    if (row < Ln) {
        const float* src = Q + (size_t)row * Dn + c;
        float4 a = *(const float4*)src;
        float4 b = *(const float4*)(src + 4);
        o.x = pack2(a.x, a.y); o.y = pack2(a.z, a.w);
        o.z = pack2(b.x, b.y); o.w = pack2(b.z, b.w);
    }
    *(uint4*)(Qb + (size_t)id * 8) = o;
}

// ---------------------------------------------------------------------------
// Generic NT bf16 MFMA GEMM: C[m,n] = sum_k A[m,k]*B[n,k]  (both k-major)
// 128x128 tile, BK=32, 4 waves, dual global_load_lds. n0 = blockIdx.x (fast,
// for A-tile L2/LLC reuse), m0 = blockIdx.y.
// OUT_BF16: 1 -> bf16 RNE out, 0 -> f32 out.
// EPI: 0 none, 1 elu(x+bias[n]), 2 elu(x+bias[m]).
// ---------------------------------------------------------------------------
template <int OUT_BF16, int EPI>
__global__ __launch_bounds__(256) void gemm_nt(const short* __restrict__ A,
                                               const short* __restrict__ B,
                                               const float* __restrict__ bias,
                                               void* __restrict__ Out,
                                               int K, int lda, int ldb, int ldo,
                                               int mmax,
                                               long bA, long bB, long bO) {
    const int b  = blockIdx.z;
    const int n0 = blockIdx.x * 128;
    const int m0 = blockIdx.y * 128;
    __shared__ short lA[128 * 32];
    __shared__ short lB[128 * 32];
    const int t = threadIdx.x;
    const int lane = t & 63, w = t >> 6;
    const int wm = (w & 1) * 64, wn = (w >> 1) * 64;
    const int quad = lane >> 4, l15 = lane & 15;
    f32x4 acc[4][4] = {};
    const short* Ab = A + (size_t)bA * b + (size_t)m0 * lda;
    const short* Bb = B + (size_t)bB * b + (size_t)n0 * ldb;
    const int sr = t >> 2, ss = (t & 3) * 8;

    for (int k0 = 0; k0 < K; k0 += 32) {
        gld_lds16(Ab + (size_t)sr * lda + k0 + ss,        lA + t * 8);
        gld_lds16(Ab + (size_t)(sr + 64) * lda + k0 + ss, lA + 2048 + t * 8);
        gld_lds16(Bb + (size_t)sr * ldb + k0 + ss,        lB + t * 8);
        gld_lds16(Bb + (size_t)(sr + 64) * ldb + k0 + ss, lB + 2048 + t * 8);
        __syncthreads();
        bf16x8 af[4], bfr[4];
#pragma unroll
        for (int i = 0; i < 4; ++i)
            af[i] = *(const bf16x8*)&lA[(wm + i * 16 + l15) * 32 + quad * 8];
#pragma unroll
        for (int j = 0; j < 4; ++j)
            bfr[j] = *(const bf16x8*)&lB[(wn + j * 16 + l15) * 32 + quad * 8];
#pragma unroll
        for (int i = 0; i < 4; ++i)
#pragma unroll
            for (int j = 0; j < 4; ++j)
                acc[i][j] = __builtin_amdgcn_mfma_f32_16x16x32_bf16(af[i], bfr[j], acc[i][j], 0, 0, 0);
        __syncthreads();
    }

#pragma unroll
    for (int i = 0; i < 4; ++i) {
        int mb = m0 + wm + i * 16 + quad * 4;
#pragma unroll
        for (int r = 0; r < 4; ++r) {
            int m = mb + r;
            if (m < mmax) {
                float bm = (EPI == 2) ? bias[m] : 0.f;
#pragma unroll
                for (int j = 0; j < 4; ++j) {
                    int col = n0 + wn + j * 16 + l15;
                    float v = acc[i][j][r];
                    if (EPI == 1) v = elu1(v + bias[col]);
                    if (EPI == 2) v = elu1(v + bm);
                    if (OUT_BF16)
                        ((short*)Out)[(size_t)bO * b + (size_t)m * ldo + col] = (short)f2bf(v);
                    else
                        ((float*)Out)[(size_t)bO * b + (size_t)m * ldo + col] = v;
                }
            }
        }
    }
}

// ---------------------------------------------------------------------------
// Softmax (primary): reads bf16 E in ws, writes f32 A (output) + bf16 A in place
// ---------------------------------------------------------------------------
__global__ __launch_bounds__(256) void softmax_bf16(short* __restrict__ EA,
                                                    float* __restrict__ Aout) {
    int row = blockIdx.x;  // 0..B*Ln-1
    int b = row / Ln, l = row - b * Ln;
    short* pe = EA + ((size_t)b * Lpad + l) * Sn;
    float* pa = Aout + (size_t)row * Sn;
    int t = threadIdx.x;
    uint4 raw = *(const uint4*)(pe + t * 8);
    unsigned pw[4] = {raw.x, raw.y, raw.z, raw.w};
    float v[8];
#pragma unroll
    for (int q = 0; q < 4; ++q) {
        v[2 * q]     = __uint_as_float(pw[q] << 16);
        v[2 * q + 1] = __uint_as_float(pw[q] & 0xFFFF0000u);
    }
    float m = v[0];
#pragma unroll
    for (int i = 1; i < 8; ++i) m = fmaxf(m, v[i]);
#pragma unroll
    for (int off = 32; off >= 1; off >>= 1) m = fmaxf(m, __shfl_xor(m, off));
    __shared__ float sm[4], ssum[4];
    int lane = t & 63, wv = t >> 6;
    if (lane == 0) sm[wv] = m;
    __syncthreads();
    m = fmaxf(fmaxf(sm[0], sm[1]), fmaxf(sm[2], sm[3]));
    float s = 0.f;
#pragma unroll
    for (int i = 0; i < 8; ++i) {
        v[i] = expf(v[i] - m);
        s += v[i];
    }
#pragma unroll
    for (int off = 32; off >= 1; off >>= 1) s += __shfl_xor(s, off);
    if (lane == 0) ssum[wv] = s;
    __syncthreads();
    s = ssum[0] + ssum[1] + ssum[2] + ssum[3];
    float inv = 1.f / s;
#pragma unroll
    for (int i = 0; i < 8; ++i) v[i] *= inv;
    float4 o0 = {v[0], v[1], v[2], v[3]};
    float4 o1 = {v[4], v[5], v[6], v[7]};
    *(float4*)(pa + t * 8)     = o0;
    *(float4*)(pa + t * 8 + 4) = o1;
    uint4 ob = {pack2(v[0], v[1]), pack2(v[2], v[3]), pack2(v[4], v[5]), pack2(v[6], v[7])};
    *(uint4*)(pe + t * 8) = ob;
}

// Softmax (fallback): f32 in place on the A output region
__global__ __launch_bounds__(256) void softmax_f32(float* __restrict__ E) {
    size_t row = blockIdx.x;
    float* p = E + row * (size_t)Sn;
    int t = threadIdx.x;
    float4 u0 = *(const float4*)(p + t * 8);
    float4 u1 = *(const float4*)(p + t * 8 + 4);
    float v[8] = {u0.x, u0.y, u0.z, u0.w, u1.x, u1.y, u1.z, u1.w};
    float m = v[0];
#pragma unroll
    for (int i = 1; i < 8; ++i) m = fmaxf(m, v[i]);
#pragma unroll
    for (int off = 32; off >= 1; off >>= 1) m = fmaxf(m, __shfl_xor(m, off));
    __shared__ float sm[4], ssum[4];
    int lane = t & 63, wv = t >> 6;
    if (lane == 0) sm[wv] = m;
    __syncthreads();
    m = fmaxf(fmaxf(sm[0], sm[1]), fmaxf(sm[2], sm[3]));
    float s = 0.f;
#pragma unroll
    for (int i = 0; i < 8; ++i) {
        v[i] = expf(v[i] - m);
        s += v[i];
    }
#pragma unroll
    for (int off = 32; off >= 1; off >>= 1) s += __shfl_xor(s, off);
    if (lane == 0) ssum[wv] = s;
    __syncthreads();
    s = ssum[0] + ssum[1] + ssum[2] + ssum[3];
    float inv = 1.f / s;
#pragma unroll
    for (int i = 0; i < 8; ++i) v[i] *= inv;
    float4 o0 = {v[0], v[1], v[2], v[3]};
    float4 o1 = {v[4], v[5], v[6], v[7]};
    *(float4*)(p + t * 8)     = o0;
    *(float4*)(p + t * 8 + 4) = o1;
}

// ---------------------------------------------------------------------------
// Fallback C GEMM (R2 structure, f32 A staging; grid x=n for A reuse)
// ---------------------------------------------------------------------------
__global__ __launch_bounds__(256) void c_mfma_f32(const float* __restrict__ A,
                                                  const short* __restrict__ Vt,
                                                  float* __restrict__ C) {
    const int b  = blockIdx.z;
    const int n0 = blockIdx.x * 128;
    const int m0 = blockIdx.y * 128;
    __shared__ short lA[128 * 32];
    __shared__ short lB[128 * 32];
    const int t = threadIdx.x;
    const int lane = t & 63, w = t >> 6;
    const int wm = (w & 1) * 64, wn = (w >> 1) * 64;
    const int quad = lane >> 4, l15 = lane & 15;
    f32x4 acc[4][4] = {};
    const float* Ab = A + (size_t)b * Ln * Sn;
    const short* Bb = Vt + (size_t)b * Dn * Sn + (size_t)n0 * Sn;
    const int ar = t >> 1, ah = (t & 1) * 16;
    const int br = t >> 2, bs = (t & 3) * 8;
    const int am = m0 + ar;
    const bool arow_ok = (am < Ln);
    const float* asrc0 = Ab + (size_t)am * Sn + ah;

    for (int s0 = 0; s0 < Sn; s0 += 32) {
        gld_lds16(Bb + (size_t)br * Sn + s0 + bs,        lB + t * 8);
        gld_lds16(Bb + (size_t)(br + 64) * Sn + s0 + bs, lB + 2048 + t * 8);
        unsigned p[8] = {0, 0, 0, 0, 0, 0, 0, 0};
        if (arow_ok) {
            const float* src = asrc0 + s0;
            float4 f0 = *(const float4*)(src);
            float4 f1 = *(const float4*)(src + 4);
            float4 f2 = *(const float4*)(src + 8);
            float4 f3 = *(const float4*)(src + 12);
            p[0] = pack_bf_trunc(f0.x, f0.y); p[1] = pack_bf_trunc(f0.z, f0.w);
            p[2] = pack_bf_trunc(f1.x, f1.y); p[3] = pack_bf_trunc(f1.z, f1.w);
            p[4] = pack_bf_trunc(f2.x, f2.y); p[5] = pack_bf_trunc(f2.z, f2.w);
            p[6] = pack_bf_trunc(f3.x, f3.y); p[7] = pack_bf_trunc(f3.z, f3.w);
        }
        *(uint4*)&lA[ar * 32 + ah]     = *(uint4*)&p[0];
        *(uint4*)&lA[ar * 32 + ah + 8] = *(uint4*)&p[4];
        __syncthreads();
        bf16x8 af[4], bfr[4];
#pragma unroll
        for (int i = 0; i < 4; ++i)
            af[i] = *(const bf16x8*)&lA[(wm + i * 16 + l15) * 32 + quad * 8];
#pragma unroll
        for (int j = 0; j < 4; ++j)
            bfr[j] = *(const bf16x8*)&lB[(wn + j * 16 + l15) * 32 + quad * 8];
#pragma unroll
        for (int i = 0; i < 4; ++i)
#pragma unroll
            for (int j = 0; j < 4; ++j)
                acc[i][j] = __builtin_amdgcn_mfma_f32_16x16x32_bf16(af[i], bfr[j], acc[i][j], 0, 0, 0);
        __syncthreads();
    }

#pragma unroll
    for (int i = 0; i < 4; ++i) {
        int mb = m0 + wm + i * 16 + quad * 4;
#pragma unroll
        for (int r = 0; r < 4; ++r) {
            int m = mb + r;
            if (m < Ln) {
                float* dst = C + (size_t)b * Ln * Dn + (size_t)m * Dn + n0 + wn;
#pragma unroll
                for (int j = 0; j < 4; ++j) dst[j * 16 + l15] = acc[i][j][r];
            }
        }
    }
}

// ---------------------------------------------------------------------------
extern "C" void kernel_launch(void* const* d_in, const int* in_sizes, int n_in,
                              void* d_out, int out_size, void* d_ws, size_t ws_size,
                              hipStream_t stream) {
    const float* H  = (const float*)d_in[0];  // [B, D, S]
    const float* Wk = (const float*)d_in[1];  // [D, D]
    const float* bk = (const float*)d_in[2];  // [D]
    const float* Wv = (const float*)d_in[3];  // [D, D]
    const float* bv = (const float*)d_in[4];  // [D]
    const float* Q  = (const float*)d_in[5];  // [L, D]

    float* out  = (float*)d_out;
    float* Cout = out;                          // [B, L, D]
    float* Aout = out + (size_t)Bn * Ln * Dn;   // [B, L, S]

    // ws layout (shorts):
    short* Vt  = (short*)d_ws;                        // [B][Dn][Sn]
    short* Kb  = Vt + (size_t)Bn * Dn * Sn;           // [B][Sn][Dn]
    short* Qb  = Kb + (size_t)Bn * Sn * Dn;           // [Lpad][Dn]
    short* EAb = Qb + (size_t)Lpad * Dn;              // [B][Lpad][Sn]  (primary)
    short* Ht  = EAb;                                 // [B][Sn][Dn], dead before EAb written
    short* Wkb = Ht + (size_t)Bn * Sn * Dn;           // [Dn][Dn], dead before EAb
    short* Wvb = Wkb + (size_t)Dn * Dn;               // [Dn][Dn]

    size_t need_primary =
        2 * ((size_t)Bn * Dn * Sn + (size_t)Bn * Sn * Dn + (size_t)Lpad * Dn +
             (size_t)Bn * Lpad * Sn);
    bool big = ws_size >= need_primary;

    // 1) precision prep
    h_transpose<<<dim3(Sn / 64, Dn / 64, Bn), 256, 0, stream>>>(H, Ht);
    f32_to_bf16<<<(Dn * Dn / 8 + 255) / 256, 256, 0, stream>>>(Wk, Wkb, Dn * Dn / 8);
    f32_to_bf16<<<(Dn * Dn / 8 + 255) / 256, 256, 0, stream>>>(Wv, Wvb, Dn * Dn / 8);
    q_to_bf16<<<(Lpad * 64) / 256, 256, 0, stream>>>(Q, Qb);

    // 2) K[b][s][o] = elu(Ht·Wk^T + bk)   (M=Sn, N=Dn, K=Dn)
    gemm_nt<1, 1><<<dim3(Dn / 128, Sn / 128, Bn), 256, 0, stream>>>(
        Ht, Wkb, bk, Kb, Dn, Dn, Dn, Dn, Sn,
        (long)Sn * Dn, 0L, (long)Sn * Dn);

    // 3) Vt[b][o][s] = elu(Wv·Ht^T + bv)  (M=Dn, N=Sn, K=Dn)
    gemm_nt<1, 2><<<dim3(Sn / 128, Dn / 128, Bn), 256, 0, stream>>>(
        Wvb, Ht, bv, Vt, Dn, Dn, Dn, Sn, Dn,
        0L, (long)Sn * Dn, (long)Dn * Sn);

    if (big) {
        // 4) E bf16 -> EAb   (M=Lpad, N=Sn, K=Dn)
        gemm_nt<1, 0><<<dim3(Sn / 128, Lpad / 128, Bn), 256, 0, stream>>>(
            Qb, Kb, nullptr, EAb, Dn, Dn, Dn, Sn, Ln,
            0L, (long)Sn * Dn, (long)Lpad * Sn);
        // 5) softmax: bf16 E -> f32 A out + bf16 A in place
        softmax_bf16<<<Bn * Ln, 256, 0, stream>>>(EAb, Aout);
        // 6) C = A·V   (M=Lpad, N=Dn, K=Sn)
        gemm_nt<0, 0><<<dim3(Dn / 128, Lpad / 128, Bn), 256, 0, stream>>>(
            EAb, Vt, nullptr, Cout, Sn, Sn, Sn, Dn, Ln,
            (long)Lpad * Sn, (long)Dn * Sn, (long)Ln * Dn);
    } else {
        // fallback: f32 E in A-output region
        gemm_nt<0, 0><<<dim3(Sn / 128, Lpad / 128, Bn), 256, 0, stream>>>(
            Qb, Kb, nullptr, Aout, Dn, Dn, Dn, Sn, Ln,
            0L, (long)Sn * Dn, (long)Ln * Sn);
        softmax_f32<<<Bn * Ln, 256, 0, stream>>>(Aout);
        c_mfma_f32<<<dim3(Dn / 128, Lpad / 128, Bn), 256, 0, stream>>>(Aout, Vt, Cout);
    }
}

// Round 2
// 720.872 us; speedup vs baseline: 1.0258x; 1.0258x over previous
//
#include <hip/hip_runtime.h>
#include <math.h>

#define Bn 4
#define Dn 512
#define Sn 2048
#define Ln 8921
#define Lpad 8960   // Ln rounded up to 128 (and to 256)

typedef short bf16x8 __attribute__((ext_vector_type(8)));
typedef float f32x4 __attribute__((ext_vector_type(4)));

__device__ __forceinline__ float elu1(float x) {
    return x > 0.f ? x : expm1f(x);
}

// f32 -> bf16 round-to-nearest-even, result in low 16 bits
__device__ __forceinline__ unsigned f2bf(float f) {
    unsigned u = __float_as_uint(f);
    u += 0x7FFFu + ((u >> 16) & 1u);
    return u >> 16;
}
__device__ __forceinline__ unsigned pack2(float a, float b) {
    return f2bf(a) | (f2bf(b) << 16);
}
// truncating pack (fallback path only, R2-proven)
__device__ __forceinline__ unsigned pack_bf_trunc(float lo, float hi) {
    return __builtin_amdgcn_perm(__float_as_uint(hi), __float_as_uint(lo), 0x07060302u);
}
__device__ __forceinline__ void gld_lds16(const void* g, void* l) {
    __builtin_amdgcn_global_load_lds((const __attribute__((address_space(1))) int*)g,
                                     (__attribute__((address_space(3))) int*)l, 16, 0, 0);
}

// ---------------------------------------------------------------------------
// H [B][D][S] f32 -> Ht [B][S][D] bf16 (LDS 64x64 tile transpose)
// ---------------------------------------------------------------------------
__global__ __launch_bounds__(256) void h_transpose(const float* __restrict__ H,
                                                   short* __restrict__ Ht) {
    int b = blockIdx.z;
    int s0 = blockIdx.x * 64, d0 = blockIdx.y * 64;
    __shared__ float tile[64][65];
    int t = threadIdx.x;
    int r = t >> 4, c4 = (t & 15) * 4;
    const float* Hb = H + (size_t)b * Dn * Sn;
#pragma unroll
    for (int i = 0; i < 4; ++i) {
        float4 v = *(const float4*)(Hb + (size_t)(d0 + i * 16 + r) * Sn + s0 + c4);
        *(float4*)&tile[i * 16 + r][c4] = v;  // tile[d][s]
    }
    __syncthreads();
#pragma unroll
    for (int i = 0; i < 4; ++i) {
        int srow = i * 16 + r;
        float v0 = tile[c4 + 0][srow], v1 = tile[c4 + 1][srow];
        float v2 = tile[c4 + 2][srow], v3 = tile[c4 + 3][srow];
        uint2 o = make_uint2(pack2(v0, v1), pack2(v2, v3));
        *(uint2*)(Ht + ((size_t)b * Sn + s0 + srow) * Dn + d0 + c4) = o;
    }
}

// ---------------------------------------------------------------------------
// plain f32 -> bf16 cvt (n8 = elems/8, exact multiple)
// ---------------------------------------------------------------------------
__global__ __launch_bounds__(256) void f32_to_bf16(const float* __restrict__ src,
                                                   short* __restrict__ dst, int n8) {
    int id = blockIdx.x * 256 + threadIdx.x;
    if (id >= n8) return;
    const float* s = src + (size_t)id * 8;
    float4 a = *(const float4*)s;
    float4 b = *(const float4*)(s + 4);
    uint4 o = {pack2(a.x, a.y), pack2(a.z, a.w), pack2(b.x, b.y), pack2(b.z, b.w)};
    *(uint4*)(dst + (size_t)id * 8) = o;
}

// Q f32 [Ln][Dn] -> bf16 [Lpad][Dn], pad rows zeroed
__global__ __launch_bounds__(256) void q_to_bf16(const float* __restrict__ Q,
                                                 short* __restrict__ Qb) {
    int id = blockIdx.x * 256 + threadIdx.x;  // Lpad*64 ids, 8 elems each
    int row = id >> 6, c = (id & 63) * 8;
    uint4 o = {0, 0, 0, 0};
    if (row < Ln) {
        const float* src = Q + (size_t)row * Dn + c;
        float4 a = *(const float4*)src;
        float4 b = *(const float4*)(src + 4);
        o.x = pack2(a.x, a.y); o.y = pack2(a.z, a.w);
        o.z = pack2(b.x, b.y); o.w = pack2(b.z, b.w);
    }
    *(uint4*)(Qb + (size_t)id * 8) = o;
}

// ---------------------------------------------------------------------------
// Old 128x128 NT GEMM (kept for K/V producers + fallback path).
// ---------------------------------------------------------------------------
template <int OUT_BF16, int EPI>
__global__ __launch_bounds__(256) void gemm_nt(const short* __restrict__ A,
                                               const short* __restrict__ B,
                                               const float* __restrict__ bias,
                                               void* __restrict__ Out,
                                               int K, int lda, int ldb, int ldo,
                                               int mmax,
                                               long bA, long bB, long bO) {
    const int b  = blockIdx.z;
    const int n0 = blockIdx.x * 128;
    const int m0 = blockIdx.y * 128;
    __shared__ short lA[128 * 32];
    __shared__ short lB[128 * 32];
    const int t = threadIdx.x;
    const int lane = t & 63, w = t >> 6;
    const int wm = (w & 1) * 64, wn = (w >> 1) * 64;
    const int quad = lane >> 4, l15 = lane & 15;
    f32x4 acc[4][4] = {};
    const short* Ab = A + (size_t)bA * b + (size_t)m0 * lda;
    const short* Bb = B + (size_t)bB * b + (size_t)n0 * ldb;
    const int sr = t >> 2, ss = (t & 3) * 8;

    for (int k0 = 0; k0 < K; k0 += 32) {
        gld_lds16(Ab + (size_t)sr * lda + k0 + ss,        lA + t * 8);
        gld_lds16(Ab + (size_t)(sr + 64) * lda + k0 + ss, lA + 2048 + t * 8);
        gld_lds16(Bb + (size_t)sr * ldb + k0 + ss,        lB + t * 8);
        gld_lds16(Bb + (size_t)(sr + 64) * ldb + k0 + ss, lB + 2048 + t * 8);
        __syncthreads();
        bf16x8 af[4], bfr[4];
#pragma unroll
        for (int i = 0; i < 4; ++i)
            af[i] = *(const bf16x8*)&lA[(wm + i * 16 + l15) * 32 + quad * 8];
#pragma unroll
        for (int j = 0; j < 4; ++j)
            bfr[j] = *(const bf16x8*)&lB[(wn + j * 16 + l15) * 32 + quad * 8];
#pragma unroll
        for (int i = 0; i < 4; ++i)
#pragma unroll
            for (int j = 0; j < 4; ++j)
                acc[i][j] = __builtin_amdgcn_mfma_f32_16x16x32_bf16(af[i], bfr[j], acc[i][j], 0, 0, 0);
        __syncthreads();
    }

#pragma unroll
    for (int i = 0; i < 4; ++i) {
        int mb = m0 + wm + i * 16 + quad * 4;
#pragma unroll
        for (int r = 0; r < 4; ++r) {
            int m = mb + r;
            if (m < mmax) {
                float bm = (EPI == 2) ? bias[m] : 0.f;
#pragma unroll
                for (int j = 0; j < 4; ++j) {
                    int col = n0 + wn + j * 16 + l15;
                    float v = acc[i][j][r];
                    if (EPI == 1) v = elu1(v + bias[col]);
                    if (EPI == 2) v = elu1(v + bm);
                    if (OUT_BF16)
                        ((short*)Out)[(size_t)bO * b + (size_t)m * ldo + col] = (short)f2bf(v);
                    else
                        ((float*)Out)[(size_t)bO * b + (size_t)m * ldo + col] = v;
                }
            }
        }
    }
}

// ---------------------------------------------------------------------------
// NEW: 256x256 NT GEMM, BK=32, 8 waves (512 thr), quad-buffered LDS (128 KiB),
// counted vmcnt (never drains in steady state), 1 barrier per K-tile,
// chunk-XOR swizzled LDS (conflict-reduced ds_read_b128).
//
// Pipeline invariants (provably race-free):
//   - stage(k) issued immediately after barrier(k-3) into slot (k&3).
//   - before barrier(k): lgkmcnt(0)  -> all waves' ds_reads of tile k-1 done
//                        vmcnt(8)    -> own stage(k) landed (k+1,k+2 in flight)
//   - after barrier(k): all waves' stage(k) landed -> safe to ds_read tile k;
//     slot (k+3)&3 == (k-1)&3 was last read in iter k-1 (reads completed
//     pre-barrier via lgkmcnt(0)) -> safe to stage(k+3).
// Swizzle: 16B-chunk index c = row*4 + q; LDS position p = c ^ ((c>>3)&3)
// (involution; bits[4:3] of c = row bits[2:1]).  Both the gld_lds global
// source and the ds_read offset apply it (rule: both-sides-or-neither).
// ---------------------------------------------------------------------------
template <int OUT_BF16>
__global__ __launch_bounds__(512, 2) void gemm_nt256(const short* __restrict__ A,
                                                     const short* __restrict__ B,
                                                     void* __restrict__ Out,
                                                     int K, int lda, int ldb, int ldo,
                                                     int mmax,
                                                     long bA, long bB, long bO) {
    const int b  = blockIdx.z;
    const int n0 = blockIdx.x * 256;
    const int m0 = blockIdx.y * 256;
    __shared__ short lds[65536];  // 4 slots x (A 8192 + B 8192) shorts = 128 KiB
    const int t = threadIdx.x;           // 0..511
    const int lane = t & 63, w = t >> 6; // 8 waves
    const int wm = w >> 2, wn = w & 3;   // wave tile: rows wm*128.., cols wn*64..
    const int quad = lane >> 4, l15 = lane & 15;
    const int xr = (l15 >> 1) & 3;       // swizzle key = row bits[2:1] = l15 bits[2:1]

    const short* Ab = A + (size_t)bA * b + (size_t)m0 * lda;
    const short* Bb = B + (size_t)bB * b + (size_t)n0 * ldb;

    // stage addressing: thread t handles LDS chunks p = i*512 + t (i=0,1) of A and B.
    // global chunk that belongs at p: g = p ^ ((p>>3)&3).
    const short* srcA[2]; const short* srcB[2];
    int dstA[2], dstB[2];
#pragma unroll
    for (int i = 0; i < 2; ++i) {
        int p = i * 512 + t;
        int g = p ^ ((p >> 3) & 3);
        int row = g >> 2, q = g & 3;
        srcA[i] = Ab + (size_t)row * lda + q * 8;
        srcB[i] = Bb + (size_t)row * ldb + q * 8;
        dstA[i] = p * 8;          // short offset within slot (A half)
        dstB[i] = 8192 + p * 8;   // B half
    }

    // fragment read offsets (shorts within slot), swizzled
    int offA[8], offB[4];
#pragma unroll
    for (int m = 0; m < 8; ++m) {
        int c = (wm * 128 + m * 16 + l15) * 4 + quad;
        offA[m] = (c ^ xr) * 8;
    }
#pragma unroll
    for (int j = 0; j < 4; ++j) {
        int c = (wn * 64 + j * 16 + l15) * 4 + quad;
        offB[j] = 8192 + (c ^ xr) * 8;
    }

    f32x4 acc[8][4] = {};
    const int NK = K >> 5;

    auto STAGE = [&](int kt) {
        const int slot = (kt & 3) * 16384;
        const int ko = kt * 32;
#pragma unroll
        for (int i = 0; i < 2; ++i) {
            gld_lds16(srcA[i] + ko, &lds[slot + dstA[i]]);
            gld_lds16(srcB[i] + ko, &lds[slot + dstB[i]]);
        }
    };

    STAGE(0); STAGE(1); STAGE(2);

    for (int k = 0; k < NK; ++k) {
        asm volatile("s_waitcnt lgkmcnt(0)" ::: "memory");
        if (k < NK - 2)
            asm volatile("s_waitcnt vmcnt(8)" ::: "memory");
        else if (k == NK - 2)
            asm volatile("s_waitcnt vmcnt(4)" ::: "memory");
        else
            asm volatile("s_waitcnt vmcnt(0)" ::: "memory");
        __builtin_amdgcn_s_barrier();
        asm volatile("" ::: "memory");  // keep stage issues / ds_reads below barrier
        if (k + 3 < NK) STAGE(k + 3);
        const short* sl = &lds[(k & 3) * 16384];
        bf16x8 af[8], bfv[4];
#pragma unroll
        for (int m = 0; m < 8; ++m) af[m] = *(const bf16x8*)(sl + offA[m]);
#pragma unroll
        for (int j = 0; j < 4; ++j) bfv[j] = *(const bf16x8*)(sl + offB[j]);
#pragma unroll
        for (int m = 0; m < 8; ++m)
#pragma unroll
            for (int j = 0; j < 4; ++j)
                acc[m][j] = __builtin_amdgcn_mfma_f32_16x16x32_bf16(af[m], bfv[j], acc[m][j], 0, 0, 0);
    }

#pragma unroll
    for (int m = 0; m < 8; ++m) {
        int mb = m0 + wm * 128 + m * 16 + quad * 4;
#pragma unroll
        for (int r = 0; r < 4; ++r) {
            int mm = mb + r;
            if (mm < mmax) {
#pragma unroll
                for (int j = 0; j < 4; ++j) {
                    int col = n0 + wn * 64 + j * 16 + l15;
                    float v = acc[m][j][r];
                    if (OUT_BF16)
                        ((short*)Out)[(size_t)bO * b + (size_t)mm * ldo + col] = (short)f2bf(v);
                    else
                        ((float*)Out)[(size_t)bO * b + (size_t)mm * ldo + col] = v;
                }
            }
        }
    }
}

// ---------------------------------------------------------------------------
// Softmax (primary): reads bf16 E in ws, writes f32 A (output) + bf16 A in place
// ---------------------------------------------------------------------------
__global__ __launch_bounds__(256) void softmax_bf16(short* __restrict__ EA,
                                                    float* __restrict__ Aout) {
    int row = blockIdx.x;  // 0..B*Ln-1
    int b = row / Ln, l = row - b * Ln;
    short* pe = EA + ((size_t)b * Lpad + l) * Sn;
    float* pa = Aout + (size_t)row * Sn;
    int t = threadIdx.x;
    uint4 raw = *(const uint4*)(pe + t * 8);
    unsigned pw[4] = {raw.x, raw.y, raw.z, raw.w};
    float v[8];
#pragma unroll
    for (int q = 0; q < 4; ++q) {
        v[2 * q]     = __uint_as_float(pw[q] << 16);
        v[2 * q + 1] = __uint_as_float(pw[q] & 0xFFFF0000u);
    }
    float m = v[0];
#pragma unroll
    for (int i = 1; i < 8; ++i) m = fmaxf(m, v[i]);
#pragma unroll
    for (int off = 32; off >= 1; off >>= 1) m = fmaxf(m, __shfl_xor(m, off));
    __shared__ float sm[4], ssum[4];
    int lane = t & 63, wv = t >> 6;
    if (lane == 0) sm[wv] = m;
    __syncthreads();
    m = fmaxf(fmaxf(sm[0], sm[1]), fmaxf(sm[2], sm[3]));
    float s = 0.f;
#pragma unroll
    for (int i = 0; i < 8; ++i) {
        v[i] = expf(v[i] - m);
        s += v[i];
    }
#pragma unroll
    for (int off = 32; off >= 1; off >>= 1) s += __shfl_xor(s, off);
    if (lane == 0) ssum[wv] = s;
    __syncthreads();
    s = ssum[0] + ssum[1] + ssum[2] + ssum[3];
    float inv = 1.f / s;
#pragma unroll
    for (int i = 0; i < 8; ++i) v[i] *= inv;
    float4 o0 = {v[0], v[1], v[2], v[3]};
    float4 o1 = {v[4], v[5], v[6], v[7]};
    *(float4*)(pa + t * 8)     = o0;
    *(float4*)(pa + t * 8 + 4) = o1;
    uint4 ob = {pack2(v[0], v[1]), pack2(v[2], v[3]), pack2(v[4], v[5]), pack2(v[6], v[7])};
    *(uint4*)(pe + t * 8) = ob;
}

// Softmax (fallback): f32 in place on the A output region
__global__ __launch_bounds__(256) void softmax_f32(float* __restrict__ E) {
    size_t row = blockIdx.x;
    float* p = E + row * (size_t)Sn;
    int t = threadIdx.x;
    float4 u0 = *(const float4*)(p + t * 8);
    float4 u1 = *(const float4*)(p + t * 8 + 4);
    float v[8] = {u0.x, u0.y, u0.z, u0.w, u1.x, u1.y, u1.z, u1.w};
    float m = v[0];
#pragma unroll
    for (int i = 1; i < 8; ++i) m = fmaxf(m, v[i]);
#pragma unroll
    for (int off = 32; off >= 1; off >>= 1) m = fmaxf(m, __shfl_xor(m, off));
    __shared__ float sm[4], ssum[4];
    int lane = t & 63, wv = t >> 6;
    if (lane == 0) sm[wv] = m;
    __syncthreads();
    m = fmaxf(fmaxf(sm[0], sm[1]), fmaxf(sm[2], sm[3]));
    float s = 0.f;
#pragma unroll
    for (int i = 0; i < 8; ++i) {
        v[i] = expf(v[i] - m);
        s += v[i];
    }
#pragma unroll
    for (int off = 32; off >= 1; off >>= 1) s += __shfl_xor(s, off);
    if (lane == 0) ssum[wv] = s;
    __syncthreads();
    s = ssum[0] + ssum[1] + ssum[2] + ssum[3];
    float inv = 1.f / s;
#pragma unroll
    for (int i = 0; i < 8; ++i) v[i] *= inv;
    float4 o0 = {v[0], v[1], v[2], v[3]};
    float4 o1 = {v[4], v[5], v[6], v[7]};
    *(float4*)(p + t * 8)     = o0;
    *(float4*)(p + t * 8 + 4) = o1;
}

// ---------------------------------------------------------------------------
// Fallback C GEMM (R2 structure, f32 A staging; grid x=n for A reuse)
// ---------------------------------------------------------------------------
__global__ __launch_bounds__(256) void c_mfma_f32(const float* __restrict__ A,
                                                  const short* __restrict__ Vt,
                                                  float* __restrict__ C) {
    const int b  = blockIdx.z;
    const int n0 = blockIdx.x * 128;
    const int m0 = blockIdx.y * 128;
    __shared__ short lA[128 * 32];
    __shared__ short lB[128 * 32];
    const int t = threadIdx.x;
    const int lane = t & 63, w = t >> 6;
    const int wm = (w & 1) * 64, wn = (w >> 1) * 64;
    const int quad = lane >> 4, l15 = lane & 15;
    f32x4 acc[4][4] = {};
    const float* Ab = A + (size_t)b * Ln * Sn;
    const short* Bb = Vt + (size_t)b * Dn * Sn + (size_t)n0 * Sn;
    const int ar = t >> 1, ah = (t & 1) * 16;
    const int br = t >> 2, bs = (t & 3) * 8;
    const int am = m0 + ar;
    const bool arow_ok = (am < Ln);
    const float* asrc0 = Ab + (size_t)am * Sn + ah;

    for (int s0 = 0; s0 < Sn; s0 += 32) {
        gld_lds16(Bb + (size_t)br * Sn + s0 + bs,        lB + t * 8);
        gld_lds16(Bb + (size_t)(br + 64) * Sn + s0 + bs, lB + 2048 + t * 8);
        unsigned p[8] = {0, 0, 0, 0, 0, 0, 0, 0};
        if (arow_ok) {
            const float* src = asrc0 + s0;
            float4 f0 = *(const float4*)(src);
            float4 f1 = *(const float4*)(src + 4);
            float4 f2 = *(const float4*)(src + 8);
            float4 f3 = *(const float4*)(src + 12);
            p[0] = pack_bf_trunc(f0.x, f0.y); p[1] = pack_bf_trunc(f0.z, f0.w);
            p[2] = pack_bf_trunc(f1.x, f1.y); p[3] = pack_bf_trunc(f1.z, f1.w);
            p[4] = pack_bf_trunc(f2.x, f2.y); p[5] = pack_bf_trunc(f2.z, f2.w);
            p[6] = pack_bf_trunc(f3.x, f3.y); p[7] = pack_bf_trunc(f3.z, f3.w);
        }
        *(uint4*)&lA[ar * 32 + ah]     = *(uint4*)&p[0];
        *(uint4*)&lA[ar * 32 + ah + 8] = *(uint4*)&p[4];
        __syncthreads();
        bf16x8 af[4], bfr[4];
#pragma unroll
        for (int i = 0; i < 4; ++i)
            af[i] = *(const bf16x8*)&lA[(wm + i * 16 + l15) * 32 + quad * 8];
#pragma unroll
        for (int j = 0; j < 4; ++j)
            bfr[j] = *(const bf16x8*)&lB[(wn + j * 16 + l15) * 32 + quad * 8];
#pragma unroll
        for (int i = 0; i < 4; ++i)
#pragma unroll
            for (int j = 0; j < 4; ++j)
                acc[i][j] = __builtin_amdgcn_mfma_f32_16x16x32_bf16(af[i], bfr[j], acc[i][j], 0, 0, 0);
        __syncthreads();
    }

#pragma unroll
    for (int i = 0; i < 4; ++i) {
        int mb = m0 + wm + i * 16 + quad * 4;
#pragma unroll
        for (int r = 0; r < 4; ++r) {
            int m = mb + r;
            if (m < Ln) {
                float* dst = C + (size_t)b * Ln * Dn + (size_t)m * Dn + n0 + wn;
#pragma unroll
                for (int j = 0; j < 4; ++j) dst[j * 16 + l15] = acc[i][j][r];
            }
        }
    }
}

// ---------------------------------------------------------------------------
extern "C" void kernel_launch(void* const* d_in, const int* in_sizes, int n_in,
                              void* d_out, int out_size, void* d_ws, size_t ws_size,
                              hipStream_t stream) {
    const float* H  = (const float*)d_in[0];  // [B, D, S]
    const float* Wk = (const float*)d_in[1];  // [D, D]
    const float* bk = (const float*)d_in[2];  // [D]
    const float* Wv = (const float*)d_in[3];  // [D, D]
    const float* bv = (const float*)d_in[4];  // [D]
    const float* Q  = (const float*)d_in[5];  // [L, D]

    float* out  = (float*)d_out;
    float* Cout = out;                          // [B, L, D]
    float* Aout = out + (size_t)Bn * Ln * Dn;   // [B, L, S]

    // ws layout (shorts):
    short* Vt  = (short*)d_ws;                        // [B][Dn][Sn]
    short* Kb  = Vt + (size_t)Bn * Dn * Sn;           // [B][Sn][Dn]
    short* Qb  = Kb + (size_t)Bn * Sn * Dn;           // [Lpad][Dn]
    short* EAb = Qb + (size_t)Lpad * Dn;              // [B][Lpad][Sn]  (primary)
    short* Ht  = EAb;                                 // [B][Sn][Dn], dead before EAb written
    short* Wkb = Ht + (size_t)Bn * Sn * Dn;           // [Dn][Dn], dead before EAb
    short* Wvb = Wkb + (size_t)Dn * Dn;               // [Dn][Dn]

    size_t need_primary =
        2 * ((size_t)Bn * Dn * Sn + (size_t)Bn * Sn * Dn + (size_t)Lpad * Dn +
             (size_t)Bn * Lpad * Sn);
    bool big = ws_size >= need_primary;

    // 1) precision prep
    h_transpose<<<dim3(Sn / 64, Dn / 64, Bn), 256, 0, stream>>>(H, Ht);
    f32_to_bf16<<<(Dn * Dn / 8 + 255) / 256, 256, 0, stream>>>(Wk, Wkb, Dn * Dn / 8);
    f32_to_bf16<<<(Dn * Dn / 8 + 255) / 256, 256, 0, stream>>>(Wv, Wvb, Dn * Dn / 8);
    q_to_bf16<<<(Lpad * 64) / 256, 256, 0, stream>>>(Q, Qb);

    // 2) K[b][s][o] = elu(Ht·Wk^T + bk)   (M=Sn, N=Dn, K=Dn)
    gemm_nt<1, 1><<<dim3(Dn / 128, Sn / 128, Bn), 256, 0, stream>>>(
        Ht, Wkb, bk, Kb, Dn, Dn, Dn, Dn, Sn,
        (long)Sn * Dn, 0L, (long)Sn * Dn);

    // 3) Vt[b][o][s] = elu(Wv·Ht^T + bv)  (M=Dn, N=Sn, K=Dn)
    gemm_nt<1, 2><<<dim3(Sn / 128, Dn / 128, Bn), 256, 0, stream>>>(
        Wvb, Ht, bv, Vt, Dn, Dn, Dn, Sn, Dn,
        0L, (long)Sn * Dn, (long)Dn * Sn);

    if (big) {
        // 4) E bf16 -> EAb   (M=Lpad, N=Sn, K=Dn), 256^2 pipelined
        gemm_nt256<1><<<dim3(Sn / 256, Lpad / 256, Bn), 512, 0, stream>>>(
            Qb, Kb, EAb, Dn, Dn, Dn, Sn, Lpad,
            0L, (long)Sn * Dn, (long)Lpad * Sn);
        // 5) softmax: bf16 E -> f32 A out + bf16 A in place
        softmax_bf16<<<Bn * Ln, 256, 0, stream>>>(EAb, Aout);
        // 6) C = A·V   (M=Lpad, N=Dn, K=Sn), 256^2 pipelined
        gemm_nt256<0><<<dim3(Dn / 256, Lpad / 256, Bn), 512, 0, stream>>>(
            EAb, Vt, Cout, Sn, Sn, Sn, Dn, Ln,
            (long)Lpad * Sn, (long)Dn * Sn, (long)Ln * Dn);
    } else {
        // fallback: f32 E in A-output region
        gemm_nt<0, 0><<<dim3(Sn / 128, Lpad / 128, Bn), 256, 0, stream>>>(
            Qb, Kb, nullptr, Aout, Dn, Dn, Dn, Sn, Ln,
            0L, (long)Sn * Dn, (long)Ln * Sn);
        softmax_f32<<<Bn * Ln, 256, 0, stream>>>(Aout);
        c_mfma_f32<<<dim3(Dn / 128, Lpad / 128, Bn), 256, 0, stream>>>(Aout, Vt, Cout);
    }
}